// Round 4
// baseline (246.940 us; speedup 1.0000x reference)
//
#include <hip/hip_runtime.h>

// Problem constants (B=1)
#define L 512
#define CM 256
#define CZ 128
#define NC 128
#define NBINS 65

typedef float  f4 __attribute__((ext_vector_type(4)));
typedef float  f2 __attribute__((ext_vector_type(2)));
typedef int    i4 __attribute__((ext_vector_type(4)));

// Dtype model (settled): fp32 in/out, int32 residue_index.
// Output = msa_rep [1,256,128,512] fp32, then pair_rep [1,128,512,512] fp32.
// absmax 0.0039 = 1 bf16 ulp of ref max (harness ref is bf16-rounded).
//
// v3: SINGLE kernel, zero workspace. Each block recomputes its tiny per-position
// linears (a2/b2/m2) directly from tf (40 KiB, L2-resident) with the exact same
// FMA ordering as the old pre_kernel -> bitwise-identical outputs. Removes the
// pre launch + graph dependency. Pair/msa blocks interleaved by blockIdx parity
// so store-heavy pair waves overlap VALU-heavy msa waves on each CU.
//
//   even bx: pair block p = bx>>1 in [0,2048): c = p>>4, i0 = (p&15)*32
//   odd  bx: msa  block m = bx>>1 in [0,2048): c = m>>3, k0 = (m&7)*16

__global__ __launch_bounds__(256)
void fused_all(const float* __restrict__ tf,
               const int*   __restrict__ ri,
               const float* __restrict__ mf,
               const float* __restrict__ waw,
               const float* __restrict__ wab,
               const float* __restrict__ wbw,
               const float* __restrict__ wbb,
               const float* __restrict__ wpw,
               const float* __restrict__ wpb,
               const float* __restrict__ wc,
               const float* __restrict__ wcb,
               const float* __restrict__ wmw,
               const float* __restrict__ wmb,
               float* __restrict__ pair_out,
               float* __restrict__ msa_out) {
    int bx = blockIdx.x;
    int t  = threadIdx.x;

    if ((bx & 1) == 0) {
        // ---- pair: pair_rep[c,i,j] = a2[c,i] + b2[c,j] + wp[c, bin(ri_i-ri_j)]
        int p  = bx >> 1;
        int c  = p >> 4;
        int i0 = (p & 15) * 32;

        __shared__ float swp[NBINS];   // wp row for this c
        __shared__ float sa[32];       // a2 segment for rows i0..i0+31
        __shared__ int   sri[32];      // residue_index segment

        if (t < NBINS) swp[t] = wpw[c * NBINS + t];
        if (t >= 128 && t < 160) {
            // a2[c,i] = wab[c] + wpb[c] + sum_f waw[c,f]*tf[f,i]
            int i = i0 + (t - 128);
            float acc = wab[c] + wpb[c];
            const float* wa = &waw[c * 20];
            #pragma unroll
            for (int f = 0; f < 20; ++f)
                acc += wa[f] * tf[f * L + i];
            sa[t - 128] = acc;
        }
        if (t >= 192 && t < 224) sri[t - 192] = ri[i0 + (t - 192)];

        int half = t >> 7;             // waves 0,1 -> 0; waves 2,3 -> 1
        int j0   = (t & 127) * 4;

        // b2[c,j] = wbb[c] + sum_f wbw[c,f]*tf[f,j]   (4 j per thread, f4 loads)
        f4 bb;
        {
            float b0 = wbb[c];
            bb.x = b0; bb.y = b0; bb.z = b0; bb.w = b0;
            const float* wb = &wbw[c * 20];
            #pragma unroll
            for (int f = 0; f < 20; ++f) {
                f4 tv = *reinterpret_cast<const f4*>(&tf[f * L + j0]);
                float w = wb[f];       // block-uniform -> scalar
                bb.x += w * tv.x;
                bb.y += w * tv.y;
                bb.z += w * tv.z;
                bb.w += w * tv.w;
            }
        }
        i4 rj = *reinterpret_cast<const i4*>(&ri[j0]);

        __syncthreads();

        size_t base0 = ((size_t)c * L + (i0 + half)) * L + j0;

        #pragma unroll
        for (int r = 0; r < 16; ++r) {
            int il = r * 2 + half;     // wave-uniform -> LDS broadcast reads
            float ai  = sa[il];
            int   rii = sri[il];

            int d0 = min(max(rii - rj.x, -32), 32) + 32;
            int d1 = min(max(rii - rj.y, -32), 32) + 32;
            int d2 = min(max(rii - rj.z, -32), 32) + 32;
            int d3 = min(max(rii - rj.w, -32), 32) + 32;

            f4 o;
            o.x = ai + bb.x + swp[d0];
            o.y = ai + bb.y + swp[d1];
            o.z = ai + bb.z + swp[d2];
            o.w = ai + bb.w + swp[d3];

            __builtin_nontemporal_store(
                o, reinterpret_cast<f4*>(&pair_out[base0 + (size_t)r * (2 * L)]));
        }
    } else {
        // ---- msa: msa_rep[c,k,l] = sum_f wc[k,c,f]*mf[f,l] + wcb[k,c] + m2[c,l]
        int m  = bx >> 1;
        int c  = m >> 3;               // 0..255
        int k0 = (m & 7) * 16;         // 0..112
        int l0 = t * 2;

        float mfa[21], mfb[21];
        #pragma unroll
        for (int f = 0; f < 21; ++f) {
            f2 u = *reinterpret_cast<const f2*>(&mf[f * L + l0]);
            mfa[f] = u.x;
            mfb[f] = u.y;
        }
        // m2[c,l] = wmb[c] + sum_f wmw[c,f]*tf[f,l]
        f2 mm;
        {
            float m0 = wmb[c];
            mm.x = m0; mm.y = m0;
            const float* wm = &wmw[c * 20];
            #pragma unroll
            for (int f = 0; f < 20; ++f) {
                f2 u = *reinterpret_cast<const f2*>(&tf[f * L + l0]);
                float w = wm[f];       // block-uniform -> scalar
                mm.x += w * u.x;
                mm.y += w * u.y;
            }
        }

        #pragma unroll 4
        for (int kk = 0; kk < 16; ++kk) {
            int k = k0 + kk;
            const float* w = &wc[((size_t)k * CM + c) * 21];  // block-uniform -> s_load
            float bias = wcb[k * CM + c];
            float acc0 = bias + mm.x;
            float acc1 = bias + mm.y;
            #pragma unroll
            for (int f = 0; f < 21; ++f) {
                float wf = w[f];
                acc0 += wf * mfa[f];
                acc1 += wf * mfb[f];
            }
            f2 o;
            o.x = acc0;
            o.y = acc1;
            __builtin_nontemporal_store(
                o, reinterpret_cast<f2*>(&msa_out[((size_t)(c * NC + k)) * L + l0]));
        }
    }
}

extern "C" void kernel_launch(void* const* d_in, const int* in_sizes, int n_in,
                              void* d_out, int out_size, void* d_ws, size_t ws_size,
                              hipStream_t stream) {
    const float* tf  = (const float*)d_in[0];   // target_feat [1,20,512] f32
    const int*   ri  = (const int*)d_in[1];     // residue_index [1,512] i32
    const float* mf  = (const float*)d_in[2];   // msa_feat [1,21,512] f32
    const float* waw = (const float*)d_in[3];   // [128,20]
    const float* wab = (const float*)d_in[4];   // [128]
    const float* wbw = (const float*)d_in[5];   // [128,20]
    const float* wbb = (const float*)d_in[6];   // [128]
    const float* wpw = (const float*)d_in[7];   // [128,65]
    const float* wpb = (const float*)d_in[8];   // [128]
    const float* wc  = (const float*)d_in[9];   // [128,256,21]
    const float* wcb = (const float*)d_in[10];  // [128,256]
    const float* wmw = (const float*)d_in[11];  // [256,20]
    const float* wmb = (const float*)d_in[12];  // [256]

    float* out = (float*)d_out;
    float* msa_out  = out;                         // 256*128*512 elems
    float* pair_out = out + (size_t)CM * NC * L;   // 128*512*512 elems

    // Single self-contained kernel: 2048 pair blocks + 2048 msa blocks,
    // parity-interleaved. No workspace, no inter-kernel dependency.
    fused_all<<<dim3(4096), dim3(256), 0, stream>>>(
        tf, ri, mf, waw, wab, wbw, wbb, wpw, wpb, wc, wcb, wmw, wmb,
        pair_out, msa_out);
}